// Round 2
// baseline (277379.517 us; speedup 1.0000x reference)
//
#include <hip/hip_runtime.h>
#include <cstddef>

// ---------------------------------------------------------------------------
// 3-layer LSTM (1->32->32->3), T=200000 sequential steps.
// Single persistent workgroup, single wave (64 lanes), weights in registers.
// Lane l owns gates l and l+64 of layers 0 and 1:
//   lanes 0..31  hold (i_j, g_j)   for j = l
//   lanes 32..63 hold (f_j, o_j)   for j = l-32
// Gate exchange for the cell update is one __shfl_xor(.,32) pair.
// Layer 2 (12 gates): 4 lanes per gate, 8-element partial dots + butterfly.
// h vectors live in LDS (broadcast reads); c stays in registers of lanes<32.
// Accuracy: precise expf + IEEE division (correctly-rounded fp32 per step);
// the 200k-step recurrence amplifies per-step error ~5e4x, so hw-approx
// v_exp/v_rcp (round 0) overshot the 2%-of-peak threshold.
// ---------------------------------------------------------------------------

#define XCH 256  // x prefetch chunk (elements)

__device__ __forceinline__ float4 lds_ld4(const float* p) {
    float4 v; __builtin_memcpy(&v, p, sizeof(float4)); return v;
}

// act(x) = m * sigmoid(k_mag * x) + a0 computed as m/(1+expf(k*x)) + a0.
// k is -1 (sigmoid) or -2 (tanh trick) -> k*x exact (power of two).
// fmaf(m, s, a0) with m=2,a0=-1 is Sterbenz-exact for s in (0.25,1].
__device__ __forceinline__ float gate_act(float x, float k, float m, float a0) {
    float s = 1.0f / (1.0f + expf(k * x));
    return fmaf(m, s, a0);
}
__device__ __forceinline__ float tanh_p(float x) {
    float s = 1.0f / (1.0f + expf(-2.0f * x));
    return fmaf(2.0f, s, -1.0f);
}

__global__ __launch_bounds__(64, 1)
void lstm3_seq_kernel(const float* __restrict__ x,
                      const float* __restrict__ Wih0, const float* __restrict__ Whh0,
                      const float* __restrict__ bih0, const float* __restrict__ bhh0,
                      const float* __restrict__ Wih1, const float* __restrict__ Whh1,
                      const float* __restrict__ bih1, const float* __restrict__ bhh1,
                      const float* __restrict__ pre_h0, const float* __restrict__ pre_c0,
                      const float* __restrict__ Wih2, const float* __restrict__ Whh2,
                      const float* __restrict__ bih2, const float* __restrict__ bhh2,
                      const float* __restrict__ post_h0, const float* __restrict__ post_c0,
                      float* __restrict__ out, int T)
{
    const int l = threadIdx.x;        // 0..63
    __shared__ __align__(16) float h0s[32];
    __shared__ __align__(16) float h1s[32];
    __shared__ float h2s[3];
    __shared__ __align__(16) float xbuf[XCH];

    const int gA = l;                 // gate A: 0..63   (i- or f-block)
    const int gB = l + 64;            // gate B: 64..127 (g- or o-block)

    // ---- load loop-invariant weights into registers --------------------
    const float wx0A = Wih0[gA];
    const float wx0B = Wih0[gB];
    const float b0A  = bih0[gA] + bhh0[gA];
    const float b0B  = bih0[gB] + bhh0[gB];
    const float b1A  = bih1[gA] + bhh1[gA];
    const float b1B  = bih1[gB] + bhh1[gB];

    float whh0A[32], whh0B[32], wih1A[32], wih1B[32], whh1A[32], whh1B[32];
#pragma unroll
    for (int r = 0; r < 32; ++r) {
        whh0A[r] = Whh0[gA * 32 + r];
        whh0B[r] = Whh0[gB * 32 + r];
        wih1A[r] = Wih1[gA * 32 + r];
        wih1B[r] = Wih1[gB * 32 + r];
        whh1A[r] = Whh1[gA * 32 + r];
        whh1B[r] = Whh1[gB * 32 + r];
    }

    // layer 2: lanes grouped in 4 per gate. g2 = l>>2 (valid l<48), p = l&3.
    const int g2 = (l < 48) ? (l >> 2) : 0;
    const int p  = l & 3;
    float w2[8];
#pragma unroll
    for (int r = 0; r < 8; ++r) w2[r] = Wih2[g2 * 32 + p * 8 + r];
    float wr2[3];
#pragma unroll
    for (int r = 0; r < 3; ++r) wr2[r] = Whh2[g2 * 3 + r];
    const float b2 = bih2[g2] + bhh2[g2];

    // per-lane activation constants (branch-free, exact k scaling)
    const float kA = -1.0f, mA = 1.0f, a0A = 0.0f;        // i|f: sigmoid
    const float kB  = (l < 32) ? -2.0f : -1.0f;           // g: tanh | o: sigmoid
    const float mB  = (l < 32) ?  2.0f :  1.0f;
    const float a0B = (l < 32) ? -1.0f :  0.0f;
    const bool  g2tanh = (g2 >= 6 && g2 <= 8);            // layer-2 g-block
    const float k2  = g2tanh ? -2.0f : -1.0f;
    const float m2  = g2tanh ?  2.0f :  1.0f;
    const float a02 = g2tanh ? -1.0f :  0.0f;

    // ---- initial state ---------------------------------------------------
    float c0 = 0.0f, c1 = 0.0f, c2 = 0.0f;
    if (l < 32) {
        c0 = pre_c0[l];
        c1 = pre_c0[32 + l];
        h0s[l] = pre_h0[l];
        h1s[l] = pre_h0[32 + l];
    }
    if (l < 3) { c2 = post_c0[l]; h2s[l] = post_h0[l]; }
    __syncthreads();

    for (int t0 = 0; t0 < T; t0 += XCH) {
        const int n = min(XCH, T - t0);
        // stage x chunk into LDS, pre-normalized with correctly-rounded /25
        {
            const int i0 = 4 * l;
            if (i0 < n) {
                const float* xp = x + t0 + i0;
                float4 v;
                v.x = xp[0] / 25.0f;
                v.y = (i0 + 1 < n) ? xp[1] / 25.0f : 0.0f;
                v.z = (i0 + 2 < n) ? xp[2] / 25.0f : 0.0f;
                v.w = (i0 + 3 < n) ? xp[3] / 25.0f : 0.0f;
                __builtin_memcpy(&xbuf[i0], &v, sizeof(float4));
            }
        }
        __syncthreads();

        for (int k = 0; k < n; ++k) {
            const float xn = xbuf[k];

            // ================= layer 0 =================
            float aA[4] = { fmaf(xn, wx0A, b0A), 0.0f, 0.0f, 0.0f };
            float aB[4] = { fmaf(xn, wx0B, b0B), 0.0f, 0.0f, 0.0f };
#pragma unroll
            for (int q = 0; q < 8; ++q) {
                const float4 h4 = lds_ld4(&h0s[q * 4]);
                aA[0] = fmaf(h4.x, whh0A[q * 4 + 0], aA[0]);
                aA[1] = fmaf(h4.y, whh0A[q * 4 + 1], aA[1]);
                aA[2] = fmaf(h4.z, whh0A[q * 4 + 2], aA[2]);
                aA[3] = fmaf(h4.w, whh0A[q * 4 + 3], aA[3]);
                aB[0] = fmaf(h4.x, whh0B[q * 4 + 0], aB[0]);
                aB[1] = fmaf(h4.y, whh0B[q * 4 + 1], aB[1]);
                aB[2] = fmaf(h4.z, whh0B[q * 4 + 2], aB[2]);
                aB[3] = fmaf(h4.w, whh0B[q * 4 + 3], aB[3]);
            }
            float actA = gate_act((aA[0] + aA[1]) + (aA[2] + aA[3]), kA, mA, a0A);
            float actB = gate_act((aB[0] + aB[1]) + (aB[2] + aB[3]), kB, mB, a0B);
            float foA = __shfl_xor(actA, 32);              // lanes<32: f_j
            float foB = __shfl_xor(actB, 32);              // lanes<32: o_j
            if (l < 32) {
                c0 = fmaf(foA, c0, actA * actB);           // f*c + i*g
                h0s[l] = foB * tanh_p(c0);                 // o*tanh(c)
            }
            asm volatile("" ::: "memory");                 // order LDS write<read

            // ================= layer 1 =================
            float uA[4] = { b1A, 0.0f, 0.0f, 0.0f };
            float uB[4] = { 0.0f, 0.0f, 0.0f, 0.0f };
            float vA[4] = { 0.0f, 0.0f, 0.0f, 0.0f };
            float vB[4] = { b1B, 0.0f, 0.0f, 0.0f };
#pragma unroll
            for (int q = 0; q < 8; ++q) {
                const float4 h4 = lds_ld4(&h0s[q * 4]);    // new h0
                const float4 g4 = lds_ld4(&h1s[q * 4]);    // old h1
                uA[0] = fmaf(h4.x, wih1A[q * 4 + 0], uA[0]);
                uA[1] = fmaf(h4.y, wih1A[q * 4 + 1], uA[1]);
                uA[2] = fmaf(h4.z, wih1A[q * 4 + 2], uA[2]);
                uA[3] = fmaf(h4.w, wih1A[q * 4 + 3], uA[3]);
                uB[0] = fmaf(h4.x, wih1B[q * 4 + 0], uB[0]);
                uB[1] = fmaf(h4.y, wih1B[q * 4 + 1], uB[1]);
                uB[2] = fmaf(h4.z, wih1B[q * 4 + 2], uB[2]);
                uB[3] = fmaf(h4.w, wih1B[q * 4 + 3], uB[3]);
                vA[0] = fmaf(g4.x, whh1A[q * 4 + 0], vA[0]);
                vA[1] = fmaf(g4.y, whh1A[q * 4 + 1], vA[1]);
                vA[2] = fmaf(g4.z, whh1A[q * 4 + 2], vA[2]);
                vA[3] = fmaf(g4.w, whh1A[q * 4 + 3], vA[3]);
                vB[0] = fmaf(g4.x, whh1B[q * 4 + 0], vB[0]);
                vB[1] = fmaf(g4.y, whh1B[q * 4 + 1], vB[1]);
                vB[2] = fmaf(g4.z, whh1B[q * 4 + 2], vB[2]);
                vB[3] = fmaf(g4.w, whh1B[q * 4 + 3], vB[3]);
            }
            actA = gate_act(((uA[0] + uA[1]) + (uA[2] + uA[3])) +
                            ((vA[0] + vA[1]) + (vA[2] + vA[3])), kA, mA, a0A);
            actB = gate_act(((uB[0] + uB[1]) + (uB[2] + uB[3])) +
                            ((vB[0] + vB[1]) + (vB[2] + vB[3])), kB, mB, a0B);
            foA = __shfl_xor(actA, 32);
            foB = __shfl_xor(actB, 32);
            if (l < 32) {
                c1 = fmaf(foA, c1, actA * actB);
                h1s[l] = foB * tanh_p(c1);
            }
            asm volatile("" ::: "memory");

            // ================= layer 2 =================
            float e0 = 0.0f, e1 = 0.0f;
            {
                const float4 ha = lds_ld4(&h1s[p * 8 + 0]);
                const float4 hb = lds_ld4(&h1s[p * 8 + 4]);
                e0 = fmaf(ha.x, w2[0], e0); e1 = fmaf(ha.y, w2[1], e1);
                e0 = fmaf(ha.z, w2[2], e0); e1 = fmaf(ha.w, w2[3], e1);
                e0 = fmaf(hb.x, w2[4], e0); e1 = fmaf(hb.y, w2[5], e1);
                e0 = fmaf(hb.z, w2[6], e0); e1 = fmaf(hb.w, w2[7], e1);
            }
            float a2 = e0 + e1;
            a2 += __shfl_xor(a2, 1);
            a2 += __shfl_xor(a2, 2);                       // full Wih2 dot
            float rec = fmaf(wr2[2], h2s[2],
                        fmaf(wr2[1], h2s[1],
                        fmaf(wr2[0], h2s[0], b2)));
            a2 += rec;
            const float act2 = gate_act(a2, k2, m2, a02);
            const int j = (l < 3) ? l : 0;
            const float i2  = __shfl(act2,  4 * j);
            const float f2  = __shfl(act2, 12 + 4 * j);
            const float g2v = __shfl(act2, 24 + 4 * j);
            const float o2  = __shfl(act2, 36 + 4 * j);
            if (l < 3) {
                c2 = fmaf(f2, c2, i2 * g2v);
                const float h2 = o2 * tanh_p(c2);
                h2s[l] = h2;
                out[(size_t)(t0 + k) * 3 + l] = h2;
            }
            asm volatile("" ::: "memory");
        }
        __syncthreads();
    }
}

extern "C" void kernel_launch(void* const* d_in, const int* in_sizes, int n_in,
                              void* d_out, int out_size, void* d_ws, size_t ws_size,
                              hipStream_t stream)
{
    const float* x       = (const float*)d_in[0];
    const float* Wih0    = (const float*)d_in[1];
    const float* Whh0    = (const float*)d_in[2];
    const float* bih0    = (const float*)d_in[3];
    const float* bhh0    = (const float*)d_in[4];
    const float* Wih1    = (const float*)d_in[5];
    const float* Whh1    = (const float*)d_in[6];
    const float* bih1    = (const float*)d_in[7];
    const float* bhh1    = (const float*)d_in[8];
    const float* pre_h0  = (const float*)d_in[9];
    const float* pre_c0  = (const float*)d_in[10];
    const float* Wih2    = (const float*)d_in[11];
    const float* Whh2    = (const float*)d_in[12];
    const float* bih2    = (const float*)d_in[13];
    const float* bhh2    = (const float*)d_in[14];
    const float* post_h0 = (const float*)d_in[15];
    const float* post_c0 = (const float*)d_in[16];

    const int T = in_sizes[0];  // x is [T,1]

    lstm3_seq_kernel<<<dim3(1), dim3(64), 0, stream>>>(
        x, Wih0, Whh0, bih0, bhh0, Wih1, Whh1, bih1, bhh1, pre_h0, pre_c0,
        Wih2, Whh2, bih2, bhh2, post_h0, post_c0, (float*)d_out, T);
}

// Round 3
// 132460.950 us; speedup vs baseline: 2.0940x; 2.0940x over previous
//
#include <hip/hip_runtime.h>
#include <cstddef>

// ---------------------------------------------------------------------------
// 3-layer LSTM (1->32->32->3), T=200000 sequential steps.
// Systolic pipeline: one wave per layer (+1 x-prefetch wave), 256 threads,
// one workgroup, one CU. Stage s at iteration k computes time t = k - s.
// Cross-stage h vectors are double-buffered in LDS by iteration parity;
// exactly one __syncthreads per iteration. Each wave's role (incl. its own
// main loop) lives in its own top-level branch so weight arrays get
// separate register live ranges.
// Per-layer arithmetic is IDENTICAL to the round-1 passing kernel
// (precise expf + IEEE div; pairwise 4-strand dot accumulation).
// ---------------------------------------------------------------------------

#define XCH 256  // x prefetch chunk (elements), power of two

__device__ __forceinline__ float4 lds_ld4(const float* p) {
    float4 v; __builtin_memcpy(&v, p, sizeof(float4)); return v;
}

// act(x) = m * sigmoid(|k| x) + a0 computed as m/(1+expf(k*x)) + a0.
__device__ __forceinline__ float gate_act(float x, float k, float m, float a0) {
    float s = 1.0f / (1.0f + expf(k * x));
    return fmaf(m, s, a0);
}
__device__ __forceinline__ float tanh_p(float x) {
    float s = 1.0f / (1.0f + expf(-2.0f * x));
    return fmaf(2.0f, s, -1.0f);
}

__global__ __launch_bounds__(256, 1)
void lstm3_pipe_kernel(const float* __restrict__ x,
                       const float* __restrict__ Wih0, const float* __restrict__ Whh0,
                       const float* __restrict__ bih0, const float* __restrict__ bhh0,
                       const float* __restrict__ Wih1, const float* __restrict__ Whh1,
                       const float* __restrict__ bih1, const float* __restrict__ bhh1,
                       const float* __restrict__ pre_h0, const float* __restrict__ pre_c0,
                       const float* __restrict__ Wih2, const float* __restrict__ Whh2,
                       const float* __restrict__ bih2, const float* __restrict__ bhh2,
                       const float* __restrict__ post_h0, const float* __restrict__ post_c0,
                       float* __restrict__ out, int T)
{
    const int tid = threadIdx.x;
    const int w   = tid >> 6;     // wave id: 0=L0, 1=L1, 2=L2, 3=x stager
    const int l   = tid & 63;     // lane

    __shared__ __align__(16) float h0s[2][32];   // h0 double buffer
    __shared__ __align__(16) float h1s[2][32];   // h1 double buffer
    __shared__ float h2s[3];                     // h2 (wave 2 private)
    __shared__ __align__(16) float xbuf[2][XCH]; // x chunk double buffer

    const int K = T + 2;          // pipeline iterations (depth 3)

    if (w == 0) {
        // =============== wave 0: layer 0 (input 1 -> 32) ===============
        const int gA = l, gB = l + 64;
        const float wx0A = Wih0[gA];
        const float wx0B = Wih0[gB];
        const float b0A  = bih0[gA] + bhh0[gA];
        const float b0B  = bih0[gB] + bhh0[gB];
        float whh0A[32], whh0B[32];
#pragma unroll
        for (int r = 0; r < 32; ++r) {
            whh0A[r] = Whh0[gA * 32 + r];
            whh0B[r] = Whh0[gB * 32 + r];
        }
        const float kA = -1.0f, mA = 1.0f, a0A = 0.0f;
        const float kB  = (l < 32) ? -2.0f : -1.0f;
        const float mB  = (l < 32) ?  2.0f :  1.0f;
        const float a0B = (l < 32) ? -1.0f :  0.0f;

        float c0 = 0.0f;
        if (l < 32) { c0 = pre_c0[l]; h0s[1][l] = pre_h0[l]; }
        __syncthreads();

        for (int k = 0; k < K; ++k) {
            if (k < T) {
                const float xn = xbuf[(k >> 8) & 1][k & (XCH - 1)];
                const float* hp = h0s[(k + 1) & 1];   // h0(t-1)
                float aA[4] = { fmaf(xn, wx0A, b0A), 0.0f, 0.0f, 0.0f };
                float aB[4] = { fmaf(xn, wx0B, b0B), 0.0f, 0.0f, 0.0f };
#pragma unroll
                for (int q = 0; q < 8; ++q) {
                    const float4 h4 = lds_ld4(&hp[q * 4]);
                    aA[0] = fmaf(h4.x, whh0A[q * 4 + 0], aA[0]);
                    aA[1] = fmaf(h4.y, whh0A[q * 4 + 1], aA[1]);
                    aA[2] = fmaf(h4.z, whh0A[q * 4 + 2], aA[2]);
                    aA[3] = fmaf(h4.w, whh0A[q * 4 + 3], aA[3]);
                    aB[0] = fmaf(h4.x, whh0B[q * 4 + 0], aB[0]);
                    aB[1] = fmaf(h4.y, whh0B[q * 4 + 1], aB[1]);
                    aB[2] = fmaf(h4.z, whh0B[q * 4 + 2], aB[2]);
                    aB[3] = fmaf(h4.w, whh0B[q * 4 + 3], aB[3]);
                }
                const float actA = gate_act((aA[0] + aA[1]) + (aA[2] + aA[3]), kA, mA, a0A);
                const float actB = gate_act((aB[0] + aB[1]) + (aB[2] + aB[3]), kB, mB, a0B);
                const float foA = __shfl_xor(actA, 32);
                const float foB = __shfl_xor(actB, 32);
                if (l < 32) {
                    c0 = fmaf(foA, c0, actA * actB);
                    h0s[k & 1][l] = foB * tanh_p(c0);
                }
            }
            __syncthreads();
        }
    } else if (w == 1) {
        // =============== wave 1: layer 1 (32 -> 32) ===============
        const int gA = l, gB = l + 64;
        const float b1A = bih1[gA] + bhh1[gA];
        const float b1B = bih1[gB] + bhh1[gB];
        float wih1A[32], wih1B[32], whh1A[32], whh1B[32];
#pragma unroll
        for (int r = 0; r < 32; ++r) {
            wih1A[r] = Wih1[gA * 32 + r];
            wih1B[r] = Wih1[gB * 32 + r];
            whh1A[r] = Whh1[gA * 32 + r];
            whh1B[r] = Whh1[gB * 32 + r];
        }
        const float kA = -1.0f, mA = 1.0f, a0A = 0.0f;
        const float kB  = (l < 32) ? -2.0f : -1.0f;
        const float mB  = (l < 32) ?  2.0f :  1.0f;
        const float a0B = (l < 32) ? -1.0f :  0.0f;

        float c1 = 0.0f;
        if (l < 32) { c1 = pre_c0[32 + l]; h1s[0][l] = pre_h0[32 + l]; }
        __syncthreads();

        for (int k = 0; k < K; ++k) {
            if (k >= 1 && k <= T) {
                const float* hp = h0s[(k - 1) & 1];   // h0(t),   t = k-1
                const float* gp = h1s[(k - 1) & 1];   // h1(t-1)
                float uA[4] = { b1A, 0.0f, 0.0f, 0.0f };
                float uB[4] = { 0.0f, 0.0f, 0.0f, 0.0f };
                float vA[4] = { 0.0f, 0.0f, 0.0f, 0.0f };
                float vB[4] = { b1B, 0.0f, 0.0f, 0.0f };
#pragma unroll
                for (int q = 0; q < 8; ++q) {
                    const float4 h4 = lds_ld4(&hp[q * 4]);
                    const float4 g4 = lds_ld4(&gp[q * 4]);
                    uA[0] = fmaf(h4.x, wih1A[q * 4 + 0], uA[0]);
                    uA[1] = fmaf(h4.y, wih1A[q * 4 + 1], uA[1]);
                    uA[2] = fmaf(h4.z, wih1A[q * 4 + 2], uA[2]);
                    uA[3] = fmaf(h4.w, wih1A[q * 4 + 3], uA[3]);
                    uB[0] = fmaf(h4.x, wih1B[q * 4 + 0], uB[0]);
                    uB[1] = fmaf(h4.y, wih1B[q * 4 + 1], uB[1]);
                    uB[2] = fmaf(h4.z, wih1B[q * 4 + 2], uB[2]);
                    uB[3] = fmaf(h4.w, wih1B[q * 4 + 3], uB[3]);
                    vA[0] = fmaf(g4.x, whh1A[q * 4 + 0], vA[0]);
                    vA[1] = fmaf(g4.y, whh1A[q * 4 + 1], vA[1]);
                    vA[2] = fmaf(g4.z, whh1A[q * 4 + 2], vA[2]);
                    vA[3] = fmaf(g4.w, whh1A[q * 4 + 3], vA[3]);
                    vB[0] = fmaf(g4.x, whh1B[q * 4 + 0], vB[0]);
                    vB[1] = fmaf(g4.y, whh1B[q * 4 + 1], vB[1]);
                    vB[2] = fmaf(g4.z, whh1B[q * 4 + 2], vB[2]);
                    vB[3] = fmaf(g4.w, whh1B[q * 4 + 3], vB[3]);
                }
                const float actA = gate_act(((uA[0] + uA[1]) + (uA[2] + uA[3])) +
                                            ((vA[0] + vA[1]) + (vA[2] + vA[3])), kA, mA, a0A);
                const float actB = gate_act(((uB[0] + uB[1]) + (uB[2] + uB[3])) +
                                            ((vB[0] + vB[1]) + (vB[2] + vB[3])), kB, mB, a0B);
                const float foA = __shfl_xor(actA, 32);
                const float foB = __shfl_xor(actB, 32);
                if (l < 32) {
                    c1 = fmaf(foA, c1, actA * actB);
                    h1s[k & 1][l] = foB * tanh_p(c1);
                }
            }
            __syncthreads();
        }
    } else if (w == 2) {
        // =============== wave 2: layer 2 (32 -> 3) + output ===============
        const int g2 = (l < 48) ? (l >> 2) : 0;
        const int p  = l & 3;
        float w2[8];
#pragma unroll
        for (int r = 0; r < 8; ++r) w2[r] = Wih2[g2 * 32 + p * 8 + r];
        float wr2[3];
#pragma unroll
        for (int r = 0; r < 3; ++r) wr2[r] = Whh2[g2 * 3 + r];
        const float b2 = bih2[g2] + bhh2[g2];
        const bool  g2tanh = (g2 >= 6 && g2 <= 8);
        const float k2  = g2tanh ? -2.0f : -1.0f;
        const float m2  = g2tanh ?  2.0f :  1.0f;
        const float a02 = g2tanh ? -1.0f :  0.0f;

        float c2 = 0.0f;
        if (l < 3) { c2 = post_c0[l]; h2s[l] = post_h0[l]; }
        __syncthreads();

        for (int k = 0; k < K; ++k) {
            if (k >= 2) {
                const int t = k - 2;
                const float* hp = h1s[(k - 1) & 1];   // h1(t)
                float e0 = 0.0f, e1 = 0.0f;
                {
                    const float4 ha = lds_ld4(&hp[p * 8 + 0]);
                    const float4 hb = lds_ld4(&hp[p * 8 + 4]);
                    e0 = fmaf(ha.x, w2[0], e0); e1 = fmaf(ha.y, w2[1], e1);
                    e0 = fmaf(ha.z, w2[2], e0); e1 = fmaf(ha.w, w2[3], e1);
                    e0 = fmaf(hb.x, w2[4], e0); e1 = fmaf(hb.y, w2[5], e1);
                    e0 = fmaf(hb.z, w2[6], e0); e1 = fmaf(hb.w, w2[7], e1);
                }
                float a2 = e0 + e1;
                a2 += __shfl_xor(a2, 1);
                a2 += __shfl_xor(a2, 2);
                const float rec = fmaf(wr2[2], h2s[2],
                                  fmaf(wr2[1], h2s[1],
                                  fmaf(wr2[0], h2s[0], b2)));
                a2 += rec;
                const float act2 = gate_act(a2, k2, m2, a02);
                const int j = (l < 3) ? l : 0;
                const float i2  = __shfl(act2,  4 * j);
                const float f2  = __shfl(act2, 12 + 4 * j);
                const float g2v = __shfl(act2, 24 + 4 * j);
                const float o2  = __shfl(act2, 36 + 4 * j);
                if (l < 3) {
                    c2 = fmaf(f2, c2, i2 * g2v);
                    const float h2 = o2 * tanh_p(c2);
                    h2s[l] = h2;
                    out[(size_t)t * 3 + l] = h2;
                }
                asm volatile("" ::: "memory");  // keep h2s write ordered before next read
            }
            __syncthreads();
        }
    } else {
        // =============== wave 3: x prefetch + normalize ===============
        // preload chunk 0 into xbuf[0]
        {
            const int i0 = 4 * l;
            if (i0 < T) {
                const float* xp = x + i0;
                float4 v;
                v.x = xp[0] / 25.0f;
                v.y = (i0 + 1 < T) ? xp[1] / 25.0f : 0.0f;
                v.z = (i0 + 2 < T) ? xp[2] / 25.0f : 0.0f;
                v.w = (i0 + 3 < T) ? xp[3] / 25.0f : 0.0f;
                __builtin_memcpy(&xbuf[0][4 * l], &v, sizeof(float4));
            }
        }
        __syncthreads();

        for (int k = 0; k < K; ++k) {
            if (k < T && (k & (XCH - 1)) == 0) {
                const int c = (k >> 8) + 1;           // next chunk
                const int base = c * XCH;
                const int i0 = base + 4 * l;
                if (base < T && i0 < T) {
                    const float* xp = x + i0;
                    float4 v;
                    v.x = xp[0] / 25.0f;
                    v.y = (i0 + 1 < T) ? xp[1] / 25.0f : 0.0f;
                    v.z = (i0 + 2 < T) ? xp[2] / 25.0f : 0.0f;
                    v.w = (i0 + 3 < T) ? xp[3] / 25.0f : 0.0f;
                    __builtin_memcpy(&xbuf[c & 1][4 * l], &v, sizeof(float4));
                }
            }
            __syncthreads();
        }
    }
}

extern "C" void kernel_launch(void* const* d_in, const int* in_sizes, int n_in,
                              void* d_out, int out_size, void* d_ws, size_t ws_size,
                              hipStream_t stream)
{
    const float* x       = (const float*)d_in[0];
    const float* Wih0    = (const float*)d_in[1];
    const float* Whh0    = (const float*)d_in[2];
    const float* bih0    = (const float*)d_in[3];
    const float* bhh0    = (const float*)d_in[4];
    const float* Wih1    = (const float*)d_in[5];
    const float* Whh1    = (const float*)d_in[6];
    const float* bih1    = (const float*)d_in[7];
    const float* bhh1    = (const float*)d_in[8];
    const float* pre_h0  = (const float*)d_in[9];
    const float* pre_c0  = (const float*)d_in[10];
    const float* Wih2    = (const float*)d_in[11];
    const float* Whh2    = (const float*)d_in[12];
    const float* bih2    = (const float*)d_in[13];
    const float* bhh2    = (const float*)d_in[14];
    const float* post_h0 = (const float*)d_in[15];
    const float* post_c0 = (const float*)d_in[16];

    const int T = in_sizes[0];  // x is [T,1]

    lstm3_pipe_kernel<<<dim3(1), dim3(256), 0, stream>>>(
        x, Wih0, Whh0, bih0, bhh0, Wih1, Whh1, bih1, bhh1, pre_h0, pre_c0,
        Wih2, Whh2, bih2, bhh2, post_h0, post_c0, (float*)d_out, T);
}

// Round 4
// 104207.788 us; speedup vs baseline: 2.6618x; 1.2711x over previous
//
#include <hip/hip_runtime.h>
#include <cstddef>

// ---------------------------------------------------------------------------
// 3-layer LSTM (1->32->32->3), T=200000 sequential steps.
// 4-wave systolic pipeline on one CU (one wave per SIMD):
//   wave 0: layer 0           h0(t)        at iter k = t
//   wave 1: layer 1 U-part    U(t)=Wih1*h0(t)            at iter k = t+1
//   wave 2: layer 1 V-part    V(t)=Whh1*h1(t-1); h1(t)   at iter k = t+2
//   wave 3: layer 2 + output  out(t)       at iter k = t+3 (+ x prefetch)
// Cross-stage values double-buffered in LDS by iteration parity.
// Barrier = raw s_barrier with lgkmcnt-only drain: global stores of `out`
// are fire-and-forget (no vmcnt(0) drain like __syncthreads would force).
// Per-gate arithmetic is bit-identical to the round-1/2 passing kernels
// (precise expf + IEEE div; same 4-strand pairwise accumulation order).
// ---------------------------------------------------------------------------

#define XCH 256  // x prefetch chunk (elements), power of two

__device__ __forceinline__ float4 lds_ld4(const float* p) {
    float4 v; __builtin_memcpy(&v, p, sizeof(float4)); return v;
}

__device__ __forceinline__ float gate_act(float x, float k, float m, float a0) {
    float s = 1.0f / (1.0f + expf(k * x));
    return fmaf(m, s, a0);
}
__device__ __forceinline__ float tanh_p(float x) {
    float s = 1.0f / (1.0f + expf(-2.0f * x));
    return fmaf(2.0f, s, -1.0f);
}

// Workgroup barrier WITHOUT vmcnt drain: LDS writes are ordered by
// lgkmcnt(0); global stores keep flying. "memory" clobber pins all
// memory ops on their side of the barrier at compile time.
__device__ __forceinline__ void pipe_barrier() {
    asm volatile("s_waitcnt lgkmcnt(0)\n\ts_barrier" ::: "memory");
}

__global__ __launch_bounds__(256, 1)
void lstm3_pipe4_kernel(const float* __restrict__ x,
                        const float* __restrict__ Wih0, const float* __restrict__ Whh0,
                        const float* __restrict__ bih0, const float* __restrict__ bhh0,
                        const float* __restrict__ Wih1, const float* __restrict__ Whh1,
                        const float* __restrict__ bih1, const float* __restrict__ bhh1,
                        const float* __restrict__ pre_h0, const float* __restrict__ pre_c0,
                        const float* __restrict__ Wih2, const float* __restrict__ Whh2,
                        const float* __restrict__ bih2, const float* __restrict__ bhh2,
                        const float* __restrict__ post_h0, const float* __restrict__ post_c0,
                        float* __restrict__ out, int T)
{
    const int tid = threadIdx.x;
    const int w   = tid >> 6;     // 0=L0, 1=L1-U, 2=L1-V, 3=L2+x
    const int l   = tid & 63;

    __shared__ __align__(16) float h0s[2][32];    // h0 double buffer
    __shared__ __align__(16) float h1s[2][32];    // h1 double buffer
    __shared__ __align__(16) float u1s[2][128];   // layer-1 U pre-activations
    __shared__ __align__(16) float xbuf[2][XCH];  // x chunk double buffer

    const int K = T + 3;          // pipeline depth 4 -> T+3 iterations

    if (w == 0) {
        // =============== wave 0: layer 0 (1 -> 32), t = k ===============
        const int gA = l, gB = l + 64;
        const float wx0A = Wih0[gA];
        const float wx0B = Wih0[gB];
        const float b0A  = bih0[gA] + bhh0[gA];
        const float b0B  = bih0[gB] + bhh0[gB];
        float whh0A[32], whh0B[32];
#pragma unroll
        for (int r = 0; r < 32; ++r) {
            whh0A[r] = Whh0[gA * 32 + r];
            whh0B[r] = Whh0[gB * 32 + r];
        }
        const float kA = -1.0f, mA = 1.0f, a0A = 0.0f;
        const float kB  = (l < 32) ? -2.0f : -1.0f;
        const float mB  = (l < 32) ?  2.0f :  1.0f;
        const float a0B = (l < 32) ? -1.0f :  0.0f;

        float c0 = 0.0f;
        if (l < 32) { c0 = pre_c0[l]; h0s[1][l] = pre_h0[l]; }
        __syncthreads();

        for (int k = 0; k < K; ++k) {
            if (k < T) {
                const float xn = xbuf[(k >> 8) & 1][k & (XCH - 1)];
                const float* hp = h0s[(k + 1) & 1];   // h0(t-1)
                float aA[4] = { fmaf(xn, wx0A, b0A), 0.0f, 0.0f, 0.0f };
                float aB[4] = { fmaf(xn, wx0B, b0B), 0.0f, 0.0f, 0.0f };
#pragma unroll
                for (int q = 0; q < 8; ++q) {
                    const float4 h4 = lds_ld4(&hp[q * 4]);
                    aA[0] = fmaf(h4.x, whh0A[q * 4 + 0], aA[0]);
                    aA[1] = fmaf(h4.y, whh0A[q * 4 + 1], aA[1]);
                    aA[2] = fmaf(h4.z, whh0A[q * 4 + 2], aA[2]);
                    aA[3] = fmaf(h4.w, whh0A[q * 4 + 3], aA[3]);
                    aB[0] = fmaf(h4.x, whh0B[q * 4 + 0], aB[0]);
                    aB[1] = fmaf(h4.y, whh0B[q * 4 + 1], aB[1]);
                    aB[2] = fmaf(h4.z, whh0B[q * 4 + 2], aB[2]);
                    aB[3] = fmaf(h4.w, whh0B[q * 4 + 3], aB[3]);
                }
                const float actA = gate_act((aA[0] + aA[1]) + (aA[2] + aA[3]), kA, mA, a0A);
                const float actB = gate_act((aB[0] + aB[1]) + (aB[2] + aB[3]), kB, mB, a0B);
                const float foA = __shfl_xor(actA, 32);
                const float foB = __shfl_xor(actB, 32);
                if (l < 32) {
                    c0 = fmaf(foA, c0, actA * actB);
                    h0s[k & 1][l] = foB * tanh_p(c0);
                }
            }
            pipe_barrier();
        }
    } else if (w == 1) {
        // ========= wave 1: layer 1 U = Wih1 * h0(t), t = k-1 =========
        const int gA = l, gB = l + 64;
        const float b1A = bih1[gA] + bhh1[gA];
        float wih1A[32], wih1B[32];
#pragma unroll
        for (int r = 0; r < 32; ++r) {
            wih1A[r] = Wih1[gA * 32 + r];
            wih1B[r] = Wih1[gB * 32 + r];
        }
        __syncthreads();

        for (int k = 0; k < K; ++k) {
            if (k >= 1 && k <= T) {
                const float* hp = h0s[(k - 1) & 1];   // h0(t)
                float uA[4] = { b1A, 0.0f, 0.0f, 0.0f };
                float uB[4] = { 0.0f, 0.0f, 0.0f, 0.0f };
#pragma unroll
                for (int q = 0; q < 8; ++q) {
                    const float4 h4 = lds_ld4(&hp[q * 4]);
                    uA[0] = fmaf(h4.x, wih1A[q * 4 + 0], uA[0]);
                    uA[1] = fmaf(h4.y, wih1A[q * 4 + 1], uA[1]);
                    uA[2] = fmaf(h4.z, wih1A[q * 4 + 2], uA[2]);
                    uA[3] = fmaf(h4.w, wih1A[q * 4 + 3], uA[3]);
                    uB[0] = fmaf(h4.x, wih1B[q * 4 + 0], uB[0]);
                    uB[1] = fmaf(h4.y, wih1B[q * 4 + 1], uB[1]);
                    uB[2] = fmaf(h4.z, wih1B[q * 4 + 2], uB[2]);
                    uB[3] = fmaf(h4.w, wih1B[q * 4 + 3], uB[3]);
                }
                u1s[k & 1][l]      = (uA[0] + uA[1]) + (uA[2] + uA[3]);
                u1s[k & 1][l + 64] = (uB[0] + uB[1]) + (uB[2] + uB[3]);
            }
            pipe_barrier();
        }
    } else if (w == 2) {
        // ===== wave 2: layer 1 V + cell update, t = k-2 =====
        const int gA = l, gB = l + 64;
        const float b1B = bih1[gB] + bhh1[gB];
        float whh1A[32], whh1B[32];
#pragma unroll
        for (int r = 0; r < 32; ++r) {
            whh1A[r] = Whh1[gA * 32 + r];
            whh1B[r] = Whh1[gB * 32 + r];
        }
        const float kA = -1.0f, mA = 1.0f, a0A = 0.0f;
        const float kB  = (l < 32) ? -2.0f : -1.0f;
        const float mB  = (l < 32) ?  2.0f :  1.0f;
        const float a0B = (l < 32) ? -1.0f :  0.0f;

        float c1 = 0.0f;
        if (l < 32) { c1 = pre_c0[32 + l]; h1s[1][l] = pre_h0[32 + l]; }
        __syncthreads();

        for (int k = 0; k < K; ++k) {
            if (k >= 2 && k <= T + 1) {
                const float* gp = h1s[(k - 1) & 1];       // h1(t-1)
                const float UA = u1s[(k - 1) & 1][l];     // U(t) from wave 1
                const float UB = u1s[(k - 1) & 1][l + 64];
                float vA[4] = { 0.0f, 0.0f, 0.0f, 0.0f };
                float vB[4] = { b1B, 0.0f, 0.0f, 0.0f };
#pragma unroll
                for (int q = 0; q < 8; ++q) {
                    const float4 g4 = lds_ld4(&gp[q * 4]);
                    vA[0] = fmaf(g4.x, whh1A[q * 4 + 0], vA[0]);
                    vA[1] = fmaf(g4.y, whh1A[q * 4 + 1], vA[1]);
                    vA[2] = fmaf(g4.z, whh1A[q * 4 + 2], vA[2]);
                    vA[3] = fmaf(g4.w, whh1A[q * 4 + 3], vA[3]);
                    vB[0] = fmaf(g4.x, whh1B[q * 4 + 0], vB[0]);
                    vB[1] = fmaf(g4.y, whh1B[q * 4 + 1], vB[1]);
                    vB[2] = fmaf(g4.z, whh1B[q * 4 + 2], vB[2]);
                    vB[3] = fmaf(g4.w, whh1B[q * 4 + 3], vB[3]);
                }
                const float actA = gate_act(UA + ((vA[0] + vA[1]) + (vA[2] + vA[3])), kA, mA, a0A);
                const float actB = gate_act(UB + ((vB[0] + vB[1]) + (vB[2] + vB[3])), kB, mB, a0B);
                const float foA = __shfl_xor(actA, 32);
                const float foB = __shfl_xor(actB, 32);
                if (l < 32) {
                    c1 = fmaf(foA, c1, actA * actB);
                    h1s[k & 1][l] = foB * tanh_p(c1);
                }
            }
            pipe_barrier();
        }
    } else {
        // ===== wave 3: layer 2 (32 -> 3) + output, t = k-3; x prefetch =====
        const int g2 = (l < 48) ? (l >> 2) : 0;
        const int p  = l & 3;
        float w2[8];
#pragma unroll
        for (int r = 0; r < 8; ++r) w2[r] = Wih2[g2 * 32 + p * 8 + r];
        float wr2[3];
#pragma unroll
        for (int r = 0; r < 3; ++r) wr2[r] = Whh2[g2 * 3 + r];
        const float b2 = bih2[g2] + bhh2[g2];
        const bool  g2tanh = (g2 >= 6 && g2 <= 8);
        const float k2  = g2tanh ? -2.0f : -1.0f;
        const float m2  = g2tanh ?  2.0f :  1.0f;
        const float a02 = g2tanh ? -1.0f :  0.0f;

        float c2 = 0.0f;
        if (l < 3) c2 = post_c0[l];
        float h2p0 = post_h0[0], h2p1 = post_h0[1], h2p2 = post_h0[2];
        float h2v = 0.0f;

        // preload x chunk 0
        {
            const int i0 = 4 * l;
            if (i0 < T) {
                const float* xp = x + i0;
                float4 v;
                v.x = xp[0] / 25.0f;
                v.y = (i0 + 1 < T) ? xp[1] / 25.0f : 0.0f;
                v.z = (i0 + 2 < T) ? xp[2] / 25.0f : 0.0f;
                v.w = (i0 + 3 < T) ? xp[3] / 25.0f : 0.0f;
                __builtin_memcpy(&xbuf[0][i0], &v, sizeof(float4));
            }
        }
        __syncthreads();

        for (int k = 0; k < K; ++k) {
            // prefetch next x chunk once per XCH iterations (256-iter slack)
            if (k < T && (k & (XCH - 1)) == 0) {
                const int c = (k >> 8) + 1;
                const int base = c * XCH;
                const int i0 = base + 4 * l;
                if (base < T && i0 < T) {
                    const float* xp = x + i0;
                    float4 v;
                    v.x = xp[0] / 25.0f;
                    v.y = (i0 + 1 < T) ? xp[1] / 25.0f : 0.0f;
                    v.z = (i0 + 2 < T) ? xp[2] / 25.0f : 0.0f;
                    v.w = (i0 + 3 < T) ? xp[3] / 25.0f : 0.0f;
                    __builtin_memcpy(&xbuf[c & 1][4 * l], &v, sizeof(float4));
                }
            }
            if (k >= 3) {
                const int t = k - 3;
                const float* hp = h1s[(k - 1) & 1];   // h1(t)
                float e0 = 0.0f, e1 = 0.0f;
                {
                    const float4 ha = lds_ld4(&hp[p * 8 + 0]);
                    const float4 hb = lds_ld4(&hp[p * 8 + 4]);
                    e0 = fmaf(ha.x, w2[0], e0); e1 = fmaf(ha.y, w2[1], e1);
                    e0 = fmaf(ha.z, w2[2], e0); e1 = fmaf(ha.w, w2[3], e1);
                    e0 = fmaf(hb.x, w2[4], e0); e1 = fmaf(hb.y, w2[5], e1);
                    e0 = fmaf(hb.z, w2[6], e0); e1 = fmaf(hb.w, w2[7], e1);
                }
                float a2 = e0 + e1;
                a2 += __shfl_xor(a2, 1);
                a2 += __shfl_xor(a2, 2);
                const float rec = fmaf(wr2[2], h2p2,
                                  fmaf(wr2[1], h2p1,
                                  fmaf(wr2[0], h2p0, b2)));
                a2 += rec;
                const float act2 = gate_act(a2, k2, m2, a02);
                const int j = (l < 3) ? l : 0;
                const float i2  = __shfl(act2,  4 * j);
                const float f2  = __shfl(act2, 12 + 4 * j);
                const float g2v = __shfl(act2, 24 + 4 * j);
                const float o2  = __shfl(act2, 36 + 4 * j);
                if (l < 3) {
                    c2 = fmaf(f2, c2, i2 * g2v);
                    h2v = o2 * tanh_p(c2);
                    out[(size_t)t * 3 + l] = h2v;   // fire-and-forget
                }
                h2p0 = __shfl(h2v, 0);
                h2p1 = __shfl(h2v, 1);
                h2p2 = __shfl(h2v, 2);
            }
            pipe_barrier();
        }
    }
}

extern "C" void kernel_launch(void* const* d_in, const int* in_sizes, int n_in,
                              void* d_out, int out_size, void* d_ws, size_t ws_size,
                              hipStream_t stream)
{
    const float* x       = (const float*)d_in[0];
    const float* Wih0    = (const float*)d_in[1];
    const float* Whh0    = (const float*)d_in[2];
    const float* bih0    = (const float*)d_in[3];
    const float* bhh0    = (const float*)d_in[4];
    const float* Wih1    = (const float*)d_in[5];
    const float* Whh1    = (const float*)d_in[6];
    const float* bih1    = (const float*)d_in[7];
    const float* bhh1    = (const float*)d_in[8];
    const float* pre_h0  = (const float*)d_in[9];
    const float* pre_c0  = (const float*)d_in[10];
    const float* Wih2    = (const float*)d_in[11];
    const float* Whh2    = (const float*)d_in[12];
    const float* bih2    = (const float*)d_in[13];
    const float* bhh2    = (const float*)d_in[14];
    const float* post_h0 = (const float*)d_in[15];
    const float* post_c0 = (const float*)d_in[16];

    const int T = in_sizes[0];  // x is [T,1]

    lstm3_pipe4_kernel<<<dim3(1), dim3(256), 0, stream>>>(
        x, Wih0, Whh0, bih0, bhh0, Wih1, Whh1, bih1, bhh1, pre_h0, pre_c0,
        Wih2, Whh2, bih2, bhh2, post_h0, post_c0, (float*)d_out, T);
}

// Round 5
// 85989.575 us; speedup vs baseline: 3.2257x; 1.2119x over previous
//
#include <hip/hip_runtime.h>
#include <cstddef>

// ---------------------------------------------------------------------------
// 3-layer LSTM (1->32->32->3), T=200000 sequential steps.
// 4-wave systolic pipeline on one CU (one wave per SIMD):
//   wave 0: layer 0           h0(t)                      at iter k = t
//   wave 1: layer 1 U-part    U(t)=Wih1*h0(t)            at iter k = t+1
//   wave 2: layer 1 V-part    V(t)=Whh1*h1(t-1); h1(t)   at iter k = t+2
//   wave 3: layer 2 + output  out(t)  (+ x prefetch)     at iter k = t+3
// Cross-stage values double-buffered in LDS by iteration parity.
// Barrier = raw s_barrier with lgkmcnt-only drain (stores fire-and-forget).
//
// R4: critical waves 0/2 use a ~45-cycle activation path:
//   exp(z) via v_exp_f32 with residual-compensated argument
//   (dt = fma(z,L2E,-t) + z*L2E_LO; e = e0*(1+dt*ln2))  -- kills the
//   argument-rounding error that sank round 0 -- and 1/(1+e) via
//   v_rcp_f32 + one Newton step (~0.5 ulp).
// Wave 3 (huge slack) keeps precise libm expf + IEEE div.
// ---------------------------------------------------------------------------

#define XCH 256  // x prefetch chunk (elements), power of two

__device__ __forceinline__ float4 lds_ld4(const float* p) {
    float4 v; __builtin_memcpy(&v, p, sizeof(float4)); return v;
}

// ---- precise path (wave 3 only) ----
__device__ __forceinline__ float gate_act(float x, float k, float m, float a0) {
    float s = 1.0f / (1.0f + expf(k * x));
    return fmaf(m, s, a0);
}
__device__ __forceinline__ float tanh_p(float x) {
    float s = 1.0f / (1.0f + expf(-2.0f * x));
    return fmaf(2.0f, s, -1.0f);
}

// ---- fast path (waves 0/2): m * sigmoid over exp(z), z = k*x (k = -1|-2,
// exact scaling). act = m / (1 + exp(z)) + a0.
__device__ __forceinline__ float v_exp2(float x) {
    float r; asm("v_exp_f32 %0, %1" : "=v"(r) : "v"(x)); return r;
}
__device__ __forceinline__ float v_rcp(float x) {
    float r; asm("v_rcp_f32 %0, %1" : "=v"(r) : "v"(x)); return r;
}
__device__ __forceinline__ float fast_gate(float z, float m, float a0) {
    const float L2E    = 1.44269502162933349609375f;  // fl32(log2 e)
    const float L2E_LO = 1.9259629911e-8f;            // log2 e - L2E
    const float LN2    = 0.69314718055994530942f;
    const float t  = z * L2E;
    const float r  = fmaf(z, L2E, -t);        // exact mul residual
    const float dt = fmaf(z, L2E_LO, r);      // total arg correction
    const float e0 = v_exp2(t);
    const float e  = fmaf(e0, dt * LN2, e0);  // 2^(t+dt) ~ e0*(1+dt*ln2)
    const float den = 1.0f + e;
    const float r0 = v_rcp(den);
    const float er = fmaf(-den, r0, 1.0f);
    const float r1 = fmaf(r0, er, r0);        // Newton: ~0.5 ulp
    return fmaf(m, r1, a0);
}
__device__ __forceinline__ float fast_tanh(float c) {
    return fast_gate(-2.0f * c, 2.0f, -1.0f);
}

// Workgroup barrier WITHOUT vmcnt drain: LDS writes ordered by lgkmcnt(0);
// global stores keep flying.
__device__ __forceinline__ void pipe_barrier() {
    asm volatile("s_waitcnt lgkmcnt(0)\n\ts_barrier" ::: "memory");
}

__global__ __launch_bounds__(256, 1)
void lstm3_pipe4_kernel(const float* __restrict__ x,
                        const float* __restrict__ Wih0, const float* __restrict__ Whh0,
                        const float* __restrict__ bih0, const float* __restrict__ bhh0,
                        const float* __restrict__ Wih1, const float* __restrict__ Whh1,
                        const float* __restrict__ bih1, const float* __restrict__ bhh1,
                        const float* __restrict__ pre_h0, const float* __restrict__ pre_c0,
                        const float* __restrict__ Wih2, const float* __restrict__ Whh2,
                        const float* __restrict__ bih2, const float* __restrict__ bhh2,
                        const float* __restrict__ post_h0, const float* __restrict__ post_c0,
                        float* __restrict__ out, int T)
{
    const int tid = threadIdx.x;
    const int w   = tid >> 6;     // 0=L0, 1=L1-U, 2=L1-V, 3=L2+x
    const int l   = tid & 63;

    __shared__ __align__(16) float h0s[2][32];    // h0 double buffer
    __shared__ __align__(16) float h1s[2][32];    // h1 double buffer
    __shared__ __align__(16) float u1s[2][128];   // layer-1 U pre-activations
    __shared__ __align__(16) float xbuf[2][XCH];  // x chunk double buffer

    const int K = T + 3;          // pipeline depth 4 -> T+3 iterations

    if (w == 0) {
        // =============== wave 0: layer 0 (1 -> 32), t = k ===============
        const int gA = l, gB = l + 64;
        const float wx0A = Wih0[gA];
        const float wx0B = Wih0[gB];
        const float b0A  = bih0[gA] + bhh0[gA];
        const float b0B  = bih0[gB] + bhh0[gB];
        float whh0A[32], whh0B[32];
#pragma unroll
        for (int r = 0; r < 32; ++r) {
            whh0A[r] = Whh0[gA * 32 + r];
            whh0B[r] = Whh0[gB * 32 + r];
        }
        const float kA = -1.0f, mA = 1.0f, a0A = 0.0f;
        const float kB  = (l < 32) ? -2.0f : -1.0f;
        const float mB  = (l < 32) ?  2.0f :  1.0f;
        const float a0B = (l < 32) ? -1.0f :  0.0f;

        float c0 = 0.0f;
        if (l < 32) { c0 = pre_c0[l]; h0s[1][l] = pre_h0[l]; }
        __syncthreads();

        for (int k = 0; k < K; ++k) {
            if (k < T) {
                const float xn = xbuf[(k >> 8) & 1][k & (XCH - 1)];
                const float* hp = h0s[(k + 1) & 1];   // h0(t-1)
                float aA[4] = { fmaf(xn, wx0A, b0A), 0.0f, 0.0f, 0.0f };
                float aB[4] = { fmaf(xn, wx0B, b0B), 0.0f, 0.0f, 0.0f };
#pragma unroll
                for (int q = 0; q < 8; ++q) {
                    const float4 h4 = lds_ld4(&hp[q * 4]);
                    aA[0] = fmaf(h4.x, whh0A[q * 4 + 0], aA[0]);
                    aA[1] = fmaf(h4.y, whh0A[q * 4 + 1], aA[1]);
                    aA[2] = fmaf(h4.z, whh0A[q * 4 + 2], aA[2]);
                    aA[3] = fmaf(h4.w, whh0A[q * 4 + 3], aA[3]);
                    aB[0] = fmaf(h4.x, whh0B[q * 4 + 0], aB[0]);
                    aB[1] = fmaf(h4.y, whh0B[q * 4 + 1], aB[1]);
                    aB[2] = fmaf(h4.z, whh0B[q * 4 + 2], aB[2]);
                    aB[3] = fmaf(h4.w, whh0B[q * 4 + 3], aB[3]);
                }
                const float actA = fast_gate(kA * ((aA[0] + aA[1]) + (aA[2] + aA[3])), mA, a0A);
                const float actB = fast_gate(kB * ((aB[0] + aB[1]) + (aB[2] + aB[3])), mB, a0B);
                const float foA = __shfl_xor(actA, 32);
                const float foB = __shfl_xor(actB, 32);
                if (l < 32) {
                    c0 = fmaf(foA, c0, actA * actB);
                    h0s[k & 1][l] = foB * fast_tanh(c0);
                }
            }
            pipe_barrier();
        }
    } else if (w == 1) {
        // ========= wave 1: layer 1 U = Wih1 * h0(t), t = k-1 =========
        const int gA = l, gB = l + 64;
        const float b1A = bih1[gA] + bhh1[gA];
        float wih1A[32], wih1B[32];
#pragma unroll
        for (int r = 0; r < 32; ++r) {
            wih1A[r] = Wih1[gA * 32 + r];
            wih1B[r] = Wih1[gB * 32 + r];
        }
        __syncthreads();

        for (int k = 0; k < K; ++k) {
            if (k >= 1 && k <= T) {
                const float* hp = h0s[(k - 1) & 1];   // h0(t)
                float uA[4] = { b1A, 0.0f, 0.0f, 0.0f };
                float uB[4] = { 0.0f, 0.0f, 0.0f, 0.0f };
#pragma unroll
                for (int q = 0; q < 8; ++q) {
                    const float4 h4 = lds_ld4(&hp[q * 4]);
                    uA[0] = fmaf(h4.x, wih1A[q * 4 + 0], uA[0]);
                    uA[1] = fmaf(h4.y, wih1A[q * 4 + 1], uA[1]);
                    uA[2] = fmaf(h4.z, wih1A[q * 4 + 2], uA[2]);
                    uA[3] = fmaf(h4.w, wih1A[q * 4 + 3], uA[3]);
                    uB[0] = fmaf(h4.x, wih1B[q * 4 + 0], uB[0]);
                    uB[1] = fmaf(h4.y, wih1B[q * 4 + 1], uB[1]);
                    uB[2] = fmaf(h4.z, wih1B[q * 4 + 2], uB[2]);
                    uB[3] = fmaf(h4.w, wih1B[q * 4 + 3], uB[3]);
                }
                u1s[k & 1][l]      = (uA[0] + uA[1]) + (uA[2] + uA[3]);
                u1s[k & 1][l + 64] = (uB[0] + uB[1]) + (uB[2] + uB[3]);
            }
            pipe_barrier();
        }
    } else if (w == 2) {
        // ===== wave 2: layer 1 V + cell update, t = k-2 =====
        const int gA = l, gB = l + 64;
        const float b1B = bih1[gB] + bhh1[gB];
        float whh1A[32], whh1B[32];
#pragma unroll
        for (int r = 0; r < 32; ++r) {
            whh1A[r] = Whh1[gA * 32 + r];
            whh1B[r] = Whh1[gB * 32 + r];
        }
        const float kA = -1.0f, mA = 1.0f, a0A = 0.0f;
        const float kB  = (l < 32) ? -2.0f : -1.0f;
        const float mB  = (l < 32) ?  2.0f :  1.0f;
        const float a0B = (l < 32) ? -1.0f :  0.0f;

        float c1 = 0.0f;
        if (l < 32) { c1 = pre_c0[32 + l]; h1s[1][l] = pre_h0[32 + l]; }
        __syncthreads();

        for (int k = 0; k < K; ++k) {
            if (k >= 2 && k <= T + 1) {
                const float* gp = h1s[(k - 1) & 1];       // h1(t-1)
                const float UA = u1s[(k - 1) & 1][l];     // U(t) from wave 1
                const float UB = u1s[(k - 1) & 1][l + 64];
                float vA[4] = { 0.0f, 0.0f, 0.0f, 0.0f };
                float vB[4] = { b1B, 0.0f, 0.0f, 0.0f };
#pragma unroll
                for (int q = 0; q < 8; ++q) {
                    const float4 g4 = lds_ld4(&gp[q * 4]);
                    vA[0] = fmaf(g4.x, whh1A[q * 4 + 0], vA[0]);
                    vA[1] = fmaf(g4.y, whh1A[q * 4 + 1], vA[1]);
                    vA[2] = fmaf(g4.z, whh1A[q * 4 + 2], vA[2]);
                    vA[3] = fmaf(g4.w, whh1A[q * 4 + 3], vA[3]);
                    vB[0] = fmaf(g4.x, whh1B[q * 4 + 0], vB[0]);
                    vB[1] = fmaf(g4.y, whh1B[q * 4 + 1], vB[1]);
                    vB[2] = fmaf(g4.z, whh1B[q * 4 + 2], vB[2]);
                    vB[3] = fmaf(g4.w, whh1B[q * 4 + 3], vB[3]);
                }
                const float sA = UA + ((vA[0] + vA[1]) + (vA[2] + vA[3]));
                const float sB = UB + ((vB[0] + vB[1]) + (vB[2] + vB[3]));
                const float actA = fast_gate(kA * sA, mA, a0A);
                const float actB = fast_gate(kB * sB, mB, a0B);
                const float foA = __shfl_xor(actA, 32);
                const float foB = __shfl_xor(actB, 32);
                if (l < 32) {
                    c1 = fmaf(foA, c1, actA * actB);
                    h1s[k & 1][l] = foB * fast_tanh(c1);
                }
            }
            pipe_barrier();
        }
    } else {
        // ===== wave 3: layer 2 (32 -> 3) + output, t = k-3; x prefetch =====
        const int g2 = (l < 48) ? (l >> 2) : 0;
        const int p  = l & 3;
        float w2[8];
#pragma unroll
        for (int r = 0; r < 8; ++r) w2[r] = Wih2[g2 * 32 + p * 8 + r];
        float wr2[3];
#pragma unroll
        for (int r = 0; r < 3; ++r) wr2[r] = Whh2[g2 * 3 + r];
        const float b2 = bih2[g2] + bhh2[g2];
        const bool  g2tanh = (g2 >= 6 && g2 <= 8);
        const float k2  = g2tanh ? -2.0f : -1.0f;
        const float m2  = g2tanh ?  2.0f :  1.0f;
        const float a02 = g2tanh ? -1.0f :  0.0f;

        float c2 = 0.0f;
        if (l < 3) c2 = post_c0[l];
        float h2p0 = post_h0[0], h2p1 = post_h0[1], h2p2 = post_h0[2];
        float h2v = 0.0f;

        // preload x chunk 0
        {
            const int i0 = 4 * l;
            if (i0 < T) {
                const float* xp = x + i0;
                float4 v;
                v.x = xp[0] / 25.0f;
                v.y = (i0 + 1 < T) ? xp[1] / 25.0f : 0.0f;
                v.z = (i0 + 2 < T) ? xp[2] / 25.0f : 0.0f;
                v.w = (i0 + 3 < T) ? xp[3] / 25.0f : 0.0f;
                __builtin_memcpy(&xbuf[0][i0], &v, sizeof(float4));
            }
        }
        __syncthreads();

        for (int k = 0; k < K; ++k) {
            // prefetch next x chunk once per XCH iterations
            if (k < T && (k & (XCH - 1)) == 0) {
                const int c = (k >> 8) + 1;
                const int base = c * XCH;
                const int i0 = base + 4 * l;
                if (base < T && i0 < T) {
                    const float* xp = x + i0;
                    float4 v;
                    v.x = xp[0] / 25.0f;
                    v.y = (i0 + 1 < T) ? xp[1] / 25.0f : 0.0f;
                    v.z = (i0 + 2 < T) ? xp[2] / 25.0f : 0.0f;
                    v.w = (i0 + 3 < T) ? xp[3] / 25.0f : 0.0f;
                    __builtin_memcpy(&xbuf[c & 1][4 * l], &v, sizeof(float4));
                }
            }
            if (k >= 3) {
                const int t = k - 3;
                const float* hp = h1s[(k - 1) & 1];   // h1(t)
                float e0 = 0.0f, e1 = 0.0f;
                {
                    const float4 ha = lds_ld4(&hp[p * 8 + 0]);
                    const float4 hb = lds_ld4(&hp[p * 8 + 4]);
                    e0 = fmaf(ha.x, w2[0], e0); e1 = fmaf(ha.y, w2[1], e1);
                    e0 = fmaf(ha.z, w2[2], e0); e1 = fmaf(ha.w, w2[3], e1);
                    e0 = fmaf(hb.x, w2[4], e0); e1 = fmaf(hb.y, w2[5], e1);
                    e0 = fmaf(hb.z, w2[6], e0); e1 = fmaf(hb.w, w2[7], e1);
                }
                float a2 = e0 + e1;
                a2 += __shfl_xor(a2, 1);
                a2 += __shfl_xor(a2, 2);
                const float rec = fmaf(wr2[2], h2p2,
                                  fmaf(wr2[1], h2p1,
                                  fmaf(wr2[0], h2p0, b2)));
                a2 += rec;
                const float act2 = gate_act(a2, k2, m2, a02);
                const int j = (l < 3) ? l : 0;
                const float i2  = __shfl(act2,  4 * j);
                const float f2  = __shfl(act2, 12 + 4 * j);
                const float g2v = __shfl(act2, 24 + 4 * j);
                const float o2  = __shfl(act2, 36 + 4 * j);
                if (l < 3) {
                    c2 = fmaf(f2, c2, i2 * g2v);
                    h2v = o2 * tanh_p(c2);
                    out[(size_t)t * 3 + l] = h2v;   // fire-and-forget
                }
                h2p0 = __shfl(h2v, 0);
                h2p1 = __shfl(h2v, 1);
                h2p2 = __shfl(h2v, 2);
            }
            pipe_barrier();
        }
    }
}

extern "C" void kernel_launch(void* const* d_in, const int* in_sizes, int n_in,
                              void* d_out, int out_size, void* d_ws, size_t ws_size,
                              hipStream_t stream)
{
    const float* x       = (const float*)d_in[0];
    const float* Wih0    = (const float*)d_in[1];
    const float* Whh0    = (const float*)d_in[2];
    const float* bih0    = (const float*)d_in[3];
    const float* bhh0    = (const float*)d_in[4];
    const float* Wih1    = (const float*)d_in[5];
    const float* Whh1    = (const float*)d_in[6];
    const float* bih1    = (const float*)d_in[7];
    const float* bhh1    = (const float*)d_in[8];
    const float* pre_h0  = (const float*)d_in[9];
    const float* pre_c0  = (const float*)d_in[10];
    const float* Wih2    = (const float*)d_in[11];
    const float* Whh2    = (const float*)d_in[12];
    const float* bih2    = (const float*)d_in[13];
    const float* bhh2    = (const float*)d_in[14];
    const float* post_h0 = (const float*)d_in[15];
    const float* post_c0 = (const float*)d_in[16];

    const int T = in_sizes[0];  // x is [T,1]

    lstm3_pipe4_kernel<<<dim3(1), dim3(256), 0, stream>>>(
        x, Wih0, Whh0, bih0, bhh0, Wih1, Whh1, bih1, bhh1, pre_h0, pre_c0,
        Wih2, Whh2, bih2, bhh2, post_h0, post_c0, (float*)d_out, T);
}

// Round 6
// 79581.311 us; speedup vs baseline: 3.4855x; 1.0805x over previous
//
#include <hip/hip_runtime.h>
#include <cstddef>

// ---------------------------------------------------------------------------
// 3-layer LSTM (1->32->32->3), T=200000 sequential steps.
// 4-wave systolic pipeline on one CU (one wave per SIMD):
//   wave 0: layer 0           h0(t)                      at iter k = t
//   wave 1: layer 1 U-part    U(t)=Wih1*h0(t)            at iter k = t+1
//   wave 2: layer 1 V-part    V(t)=Whh1*h1(t-1); h1(t)   at iter k = t+2
//   wave 3: layer 2 + output  out(t)  (+ x prefetch)     at iter k = t+3
// Cross-stage values double-buffered in LDS by iteration parity.
// Barrier = raw s_barrier with lgkmcnt-only drain (stores fire-and-forget).
//
// R5: (1) all dot products via v_pk_fma_f32 (packed fp32 FMA, bit-identical
// per-element rounding, exact same strand summation order as R2-R4) --
// halves FMA issue count on every wave; (2) wave 3 switches to the same
// residual-compensated v_exp + Newton v_rcp activation as waves 0/2
// (absmax has sat at the 2^-10 output-quantization floor for 4 rounds).
// ---------------------------------------------------------------------------

#define XCH 256  // x prefetch chunk (elements), power of two

typedef float f32x2 __attribute__((ext_vector_type(2)));

__device__ __forceinline__ f32x2 pk_fma(f32x2 a, f32x2 b, f32x2 c) {
    f32x2 d;
    asm("v_pk_fma_f32 %0, %1, %2, %3" : "=v"(d) : "v"(a), "v"(b), "v"(c));
    return d;
}
__device__ __forceinline__ f32x2 lds_ld2(const float* p) {
    f32x2 v; __builtin_memcpy(&v, p, sizeof(f32x2)); return v;
}

// ---- fast activation: act = m / (1 + exp(z)) + a0, z = k*x (k = -1|-2).
__device__ __forceinline__ float v_exp2(float x) {
    float r; asm("v_exp_f32 %0, %1" : "=v"(r) : "v"(x)); return r;
}
__device__ __forceinline__ float v_rcp(float x) {
    float r; asm("v_rcp_f32 %0, %1" : "=v"(r) : "v"(x)); return r;
}
__device__ __forceinline__ float fast_gate(float z, float m, float a0) {
    const float L2E    = 1.44269502162933349609375f;  // fl32(log2 e)
    const float L2E_LO = 1.9259629911e-8f;            // log2 e - L2E
    const float LN2    = 0.69314718055994530942f;
    const float t  = z * L2E;
    const float r  = fmaf(z, L2E, -t);        // exact mul residual
    const float dt = fmaf(z, L2E_LO, r);      // total arg correction
    const float e0 = v_exp2(t);
    const float e  = fmaf(e0, dt * LN2, e0);  // 2^(t+dt) ~ e0*(1+dt*ln2)
    const float den = 1.0f + e;
    const float r0 = v_rcp(den);
    const float er = fmaf(-den, r0, 1.0f);
    const float r1 = fmaf(r0, er, r0);        // Newton: ~0.5 ulp
    return fmaf(m, r1, a0);
}
__device__ __forceinline__ float fast_tanh(float c) {
    return fast_gate(-2.0f * c, 2.0f, -1.0f);
}

// Workgroup barrier WITHOUT vmcnt drain: LDS writes ordered by lgkmcnt(0);
// global stores keep flying.
__device__ __forceinline__ void pipe_barrier() {
    asm volatile("s_waitcnt lgkmcnt(0)\n\ts_barrier" ::: "memory");
}

__global__ __launch_bounds__(256, 1)
void lstm3_pipe5_kernel(const float* __restrict__ x,
                        const float* __restrict__ Wih0, const float* __restrict__ Whh0,
                        const float* __restrict__ bih0, const float* __restrict__ bhh0,
                        const float* __restrict__ Wih1, const float* __restrict__ Whh1,
                        const float* __restrict__ bih1, const float* __restrict__ bhh1,
                        const float* __restrict__ pre_h0, const float* __restrict__ pre_c0,
                        const float* __restrict__ Wih2, const float* __restrict__ Whh2,
                        const float* __restrict__ bih2, const float* __restrict__ bhh2,
                        const float* __restrict__ post_h0, const float* __restrict__ post_c0,
                        float* __restrict__ out, int T)
{
    const int tid = threadIdx.x;
    const int w   = tid >> 6;     // 0=L0, 1=L1-U, 2=L1-V, 3=L2+x
    const int l   = tid & 63;

    __shared__ __align__(16) float h0s[2][32];    // h0 double buffer
    __shared__ __align__(16) float h1s[2][32];    // h1 double buffer
    __shared__ __align__(16) float u1s[2][128];   // layer-1 U pre-activations
    __shared__ __align__(16) float xbuf[2][XCH];  // x chunk double buffer

    const int K = T + 3;          // pipeline depth 4 -> T+3 iterations

    if (w == 0) {
        // =============== wave 0: layer 0 (1 -> 32), t = k ===============
        const int gA = l, gB = l + 64;
        const float wx0A = Wih0[gA];
        const float wx0B = Wih0[gB];
        const float b0A  = bih0[gA] + bhh0[gA];
        const float b0B  = bih0[gB] + bhh0[gB];
        f32x2 wA2[16], wB2[16];
#pragma unroll
        for (int r = 0; r < 16; ++r) {
            wA2[r][0] = Whh0[gA * 32 + 2 * r]; wA2[r][1] = Whh0[gA * 32 + 2 * r + 1];
            wB2[r][0] = Whh0[gB * 32 + 2 * r]; wB2[r][1] = Whh0[gB * 32 + 2 * r + 1];
        }
        const float kA = -1.0f, mA = 1.0f, a0A = 0.0f;
        const float kB  = (l < 32) ? -2.0f : -1.0f;
        const float mB  = (l < 32) ?  2.0f :  1.0f;
        const float a0B = (l < 32) ? -1.0f :  0.0f;

        float c0 = 0.0f;
        if (l < 32) { c0 = pre_c0[l]; h0s[1][l] = pre_h0[l]; }
        __syncthreads();

        for (int k = 0; k < K; ++k) {
            if (k < T) {
                const float xn = xbuf[(k >> 8) & 1][k & (XCH - 1)];
                const float* hp = h0s[(k + 1) & 1];   // h0(t-1)
                f32x2 aA0, aA1, aB0, aB1;
                aA0[0] = fmaf(xn, wx0A, b0A); aA0[1] = 0.0f;
                aA1[0] = 0.0f;                aA1[1] = 0.0f;
                aB0[0] = fmaf(xn, wx0B, b0B); aB0[1] = 0.0f;
                aB1[0] = 0.0f;                aB1[1] = 0.0f;
#pragma unroll
                for (int q = 0; q < 8; ++q) {
                    const f32x2 h01 = lds_ld2(&hp[q * 4]);
                    const f32x2 h23 = lds_ld2(&hp[q * 4 + 2]);
                    aA0 = pk_fma(h01, wA2[2 * q],     aA0);
                    aA1 = pk_fma(h23, wA2[2 * q + 1], aA1);
                    aB0 = pk_fma(h01, wB2[2 * q],     aB0);
                    aB1 = pk_fma(h23, wB2[2 * q + 1], aB1);
                }
                const float sA = (aA0[0] + aA0[1]) + (aA1[0] + aA1[1]);
                const float sB = (aB0[0] + aB0[1]) + (aB1[0] + aB1[1]);
                const float actA = fast_gate(kA * sA, mA, a0A);
                const float actB = fast_gate(kB * sB, mB, a0B);
                const float foA = __shfl_xor(actA, 32);
                const float foB = __shfl_xor(actB, 32);
                if (l < 32) {
                    c0 = fmaf(foA, c0, actA * actB);
                    h0s[k & 1][l] = foB * fast_tanh(c0);
                }
            }
            pipe_barrier();
        }
    } else if (w == 1) {
        // ========= wave 1: layer 1 U = Wih1 * h0(t), t = k-1 =========
        const int gA = l, gB = l + 64;
        const float b1A = bih1[gA] + bhh1[gA];
        f32x2 wA2[16], wB2[16];
#pragma unroll
        for (int r = 0; r < 16; ++r) {
            wA2[r][0] = Wih1[gA * 32 + 2 * r]; wA2[r][1] = Wih1[gA * 32 + 2 * r + 1];
            wB2[r][0] = Wih1[gB * 32 + 2 * r]; wB2[r][1] = Wih1[gB * 32 + 2 * r + 1];
        }
        __syncthreads();

        for (int k = 0; k < K; ++k) {
            if (k >= 1 && k <= T) {
                const float* hp = h0s[(k - 1) & 1];   // h0(t)
                f32x2 uA0, uA1, uB0, uB1;
                uA0[0] = b1A;  uA0[1] = 0.0f;
                uA1[0] = 0.0f; uA1[1] = 0.0f;
                uB0[0] = 0.0f; uB0[1] = 0.0f;
                uB1[0] = 0.0f; uB1[1] = 0.0f;
#pragma unroll
                for (int q = 0; q < 8; ++q) {
                    const f32x2 h01 = lds_ld2(&hp[q * 4]);
                    const f32x2 h23 = lds_ld2(&hp[q * 4 + 2]);
                    uA0 = pk_fma(h01, wA2[2 * q],     uA0);
                    uA1 = pk_fma(h23, wA2[2 * q + 1], uA1);
                    uB0 = pk_fma(h01, wB2[2 * q],     uB0);
                    uB1 = pk_fma(h23, wB2[2 * q + 1], uB1);
                }
                u1s[k & 1][l]      = (uA0[0] + uA0[1]) + (uA1[0] + uA1[1]);
                u1s[k & 1][l + 64] = (uB0[0] + uB0[1]) + (uB1[0] + uB1[1]);
            }
            pipe_barrier();
        }
    } else if (w == 2) {
        // ===== wave 2: layer 1 V + cell update, t = k-2 =====
        const int gA = l, gB = l + 64;
        const float b1B = bih1[gB] + bhh1[gB];
        f32x2 wA2[16], wB2[16];
#pragma unroll
        for (int r = 0; r < 16; ++r) {
            wA2[r][0] = Whh1[gA * 32 + 2 * r]; wA2[r][1] = Whh1[gA * 32 + 2 * r + 1];
            wB2[r][0] = Whh1[gB * 32 + 2 * r]; wB2[r][1] = Whh1[gB * 32 + 2 * r + 1];
        }
        const float kA = -1.0f, mA = 1.0f, a0A = 0.0f;
        const float kB  = (l < 32) ? -2.0f : -1.0f;
        const float mB  = (l < 32) ?  2.0f :  1.0f;
        const float a0B = (l < 32) ? -1.0f :  0.0f;

        float c1 = 0.0f;
        if (l < 32) { c1 = pre_c0[32 + l]; h1s[1][l] = pre_h0[32 + l]; }
        __syncthreads();

        for (int k = 0; k < K; ++k) {
            if (k >= 2 && k <= T + 1) {
                const float* gp = h1s[(k - 1) & 1];       // h1(t-1)
                f32x2 vA0, vA1, vB0, vB1;
                vA0[0] = 0.0f; vA0[1] = 0.0f;
                vA1[0] = 0.0f; vA1[1] = 0.0f;
                vB0[0] = b1B;  vB0[1] = 0.0f;
                vB1[0] = 0.0f; vB1[1] = 0.0f;
#pragma unroll
                for (int q = 0; q < 8; ++q) {
                    const f32x2 g01 = lds_ld2(&gp[q * 4]);
                    const f32x2 g23 = lds_ld2(&gp[q * 4 + 2]);
                    vA0 = pk_fma(g01, wA2[2 * q],     vA0);
                    vA1 = pk_fma(g23, wA2[2 * q + 1], vA1);
                    vB0 = pk_fma(g01, wB2[2 * q],     vB0);
                    vB1 = pk_fma(g23, wB2[2 * q + 1], vB1);
                }
                const float UA = u1s[(k - 1) & 1][l];     // U(t) from wave 1
                const float UB = u1s[(k - 1) & 1][l + 64];
                const float sA = UA + ((vA0[0] + vA0[1]) + (vA1[0] + vA1[1]));
                const float sB = UB + ((vB0[0] + vB0[1]) + (vB1[0] + vB1[1]));
                const float actA = fast_gate(kA * sA, mA, a0A);
                const float actB = fast_gate(kB * sB, mB, a0B);
                const float foA = __shfl_xor(actA, 32);
                const float foB = __shfl_xor(actB, 32);
                if (l < 32) {
                    c1 = fmaf(foA, c1, actA * actB);
                    h1s[k & 1][l] = foB * fast_tanh(c1);
                }
            }
            pipe_barrier();
        }
    } else {
        // ===== wave 3: layer 2 (32 -> 3) + output, t = k-3; x prefetch =====
        const int g2 = (l < 48) ? (l >> 2) : 0;
        const int p  = l & 3;
        f32x2 w2p[4];
#pragma unroll
        for (int r = 0; r < 4; ++r) {
            w2p[r][0] = Wih2[g2 * 32 + p * 8 + 2 * r];
            w2p[r][1] = Wih2[g2 * 32 + p * 8 + 2 * r + 1];
        }
        float wr2[3];
#pragma unroll
        for (int r = 0; r < 3; ++r) wr2[r] = Whh2[g2 * 3 + r];
        const float b2 = bih2[g2] + bhh2[g2];
        const bool  g2tanh = (g2 >= 6 && g2 <= 8);
        const float k2  = g2tanh ? -2.0f : -1.0f;
        const float m2  = g2tanh ?  2.0f :  1.0f;
        const float a02 = g2tanh ? -1.0f :  0.0f;

        float c2 = 0.0f;
        if (l < 3) c2 = post_c0[l];
        float h2p0 = post_h0[0], h2p1 = post_h0[1], h2p2 = post_h0[2];
        float h2v = 0.0f;

        // preload x chunk 0
        {
            const int i0 = 4 * l;
            if (i0 < T) {
                const float* xp = x + i0;
                float4 v;
                v.x = xp[0] / 25.0f;
                v.y = (i0 + 1 < T) ? xp[1] / 25.0f : 0.0f;
                v.z = (i0 + 2 < T) ? xp[2] / 25.0f : 0.0f;
                v.w = (i0 + 3 < T) ? xp[3] / 25.0f : 0.0f;
                __builtin_memcpy(&xbuf[0][i0], &v, sizeof(float4));
            }
        }
        __syncthreads();

        for (int k = 0; k < K; ++k) {
            // prefetch next x chunk once per XCH iterations
            if (k < T && (k & (XCH - 1)) == 0) {
                const int c = (k >> 8) + 1;
                const int base = c * XCH;
                const int i0 = base + 4 * l;
                if (base < T && i0 < T) {
                    const float* xp = x + i0;
                    float4 v;
                    v.x = xp[0] / 25.0f;
                    v.y = (i0 + 1 < T) ? xp[1] / 25.0f : 0.0f;
                    v.z = (i0 + 2 < T) ? xp[2] / 25.0f : 0.0f;
                    v.w = (i0 + 3 < T) ? xp[3] / 25.0f : 0.0f;
                    __builtin_memcpy(&xbuf[c & 1][4 * l], &v, sizeof(float4));
                }
            }
            if (k >= 3) {
                const int t = k - 3;
                const float* hp = h1s[(k - 1) & 1];   // h1(t)
                f32x2 acc; acc[0] = 0.0f; acc[1] = 0.0f;
                {
                    const f32x2 a01 = lds_ld2(&hp[p * 8 + 0]);
                    const f32x2 a23 = lds_ld2(&hp[p * 8 + 2]);
                    const f32x2 b01 = lds_ld2(&hp[p * 8 + 4]);
                    const f32x2 b23 = lds_ld2(&hp[p * 8 + 6]);
                    acc = pk_fma(a01, w2p[0], acc);
                    acc = pk_fma(a23, w2p[1], acc);
                    acc = pk_fma(b01, w2p[2], acc);
                    acc = pk_fma(b23, w2p[3], acc);
                }
                float a2 = acc[0] + acc[1];
                a2 += __shfl_xor(a2, 1);
                a2 += __shfl_xor(a2, 2);
                const float rec = fmaf(wr2[2], h2p2,
                                  fmaf(wr2[1], h2p1,
                                  fmaf(wr2[0], h2p0, b2)));
                a2 += rec;
                const float act2 = fast_gate(k2 * a2, m2, a02);
                const int j = (l < 3) ? l : 0;
                const float i2  = __shfl(act2,  4 * j);
                const float f2  = __shfl(act2, 12 + 4 * j);
                const float g2v = __shfl(act2, 24 + 4 * j);
                const float o2  = __shfl(act2, 36 + 4 * j);
                if (l < 3) {
                    c2 = fmaf(f2, c2, i2 * g2v);
                    h2v = o2 * fast_tanh(c2);
                    out[(size_t)t * 3 + l] = h2v;   // fire-and-forget
                }
                h2p0 = __shfl(h2v, 0);
                h2p1 = __shfl(h2v, 1);
                h2p2 = __shfl(h2v, 2);
            }
            pipe_barrier();
        }
    }
}

extern "C" void kernel_launch(void* const* d_in, const int* in_sizes, int n_in,
                              void* d_out, int out_size, void* d_ws, size_t ws_size,
                              hipStream_t stream)
{
    const float* x       = (const float*)d_in[0];
    const float* Wih0    = (const float*)d_in[1];
    const float* Whh0    = (const float*)d_in[2];
    const float* bih0    = (const float*)d_in[3];
    const float* bhh0    = (const float*)d_in[4];
    const float* Wih1    = (const float*)d_in[5];
    const float* Whh1    = (const float*)d_in[6];
    const float* bih1    = (const float*)d_in[7];
    const float* bhh1    = (const float*)d_in[8];
    const float* pre_h0  = (const float*)d_in[9];
    const float* pre_c0  = (const float*)d_in[10];
    const float* Wih2    = (const float*)d_in[11];
    const float* Whh2    = (const float*)d_in[12];
    const float* bih2    = (const float*)d_in[13];
    const float* bhh2    = (const float*)d_in[14];
    const float* post_h0 = (const float*)d_in[15];
    const float* post_c0 = (const float*)d_in[16];

    const int T = in_sizes[0];  // x is [T,1]

    lstm3_pipe5_kernel<<<dim3(1), dim3(256), 0, stream>>>(
        x, Wih0, Whh0, bih0, bhh0, Wih1, Whh1, bih1, bhh1, pre_h0, pre_c0,
        Wih2, Whh2, bih2, bhh2, post_h0, post_c0, (float*)d_out, T);
}